// Round 8
// baseline (21.984 us; speedup 1.0000x reference)
//
#include <hip/hip_runtime.h>
#include <math.h>

// Problem constants (from reference setup_inputs): B=32, H=W=1024.
constexpr int B = 32;
constexpr int H = 1024;
constexpr int W = 1024;
constexpr int BPB  = 64;              // blocks per batch; also the row stride
constexpr int ROWS = H / BPB;         // 16 rows per block (y = blk + 64*i)
constexpr int NBLK = B * BPB;         // 2048 blocks (exactly CU-resident)
constexpr int NTHREADS = 256;         // 256 threads * float4 = one 1024-px row
constexpr int STR = BPB * W;          // floats per i-step (64 rows)

__device__ __forceinline__ float row4(const float4 v) {
    float s = 0.0f;
    s -= __logf(1.0f - v.x + 1e-7f);
    s -= __logf(1.0f - v.y + 1e-7f);
    s -= __logf(1.0f - v.z + 1e-7f);
    s -= __logf(1.0f - v.w + 1e-7f);
    return s;
}
__device__ __forceinline__ float row4w(const float4 v, const float4 w) {
    float s = 0.0f;
    s -= w.x * __logf(1.0f - v.x + 1e-7f);
    s -= w.y * __logf(1.0f - v.y + 1e-7f);
    s -= w.z * __logf(1.0f - v.z + 1e-7f);
    s -= w.w * __logf(1.0f - v.w + 1e-7f);
    return s;
}

// Kernel 1: partial sums of (1/cnt_b) * -log(1 - p + eps) over outside pixels.
// IDENTICAL inner structure to R7 (branchless 3-loop, paired loads). ONLY
// CHANGE: block->work mapping is batch-interleaved: b = g & 31, blk = g >> 5.
// The grid is exactly residency-sized (2048 blocks * 4 waves = 8192 waves =
// 256 CU * 32), so there is NO backfill -- static balance is the only
// balance. Interleaving makes each CU's resident blocks span 8 different
// batches, so per-CU work ~= global mean regardless of bbox sizes.
// Each block still touches ONE batch contiguously (TLB/L2-friendly).
__global__ __launch_bounds__(NTHREADS)
void partial_kernel(const float* __restrict__ pred,
                    const float* __restrict__ bboxes,
                    float* __restrict__ ws) {
    const int g   = blockIdx.x;
    const int b   = g & (B - 1);          // batch (interleaved)
    const int blk = g >> 5;               // row offset within batch, 0..63
    const int tid = threadIdx.x;

    // bbox -> integer pixel bounds, exactly matching the reference (scalar).
    const int x1 = max((int)floorf(bboxes[b * 4 + 0] * (float)W), 0);
    const int y1 = max((int)floorf(bboxes[b * 4 + 1] * (float)H), 0);
    const int x2 = min((int)floorf(bboxes[b * 4 + 2] * (float)W), W);
    const int y2 = min((int)floorf(bboxes[b * 4 + 3] * (float)H), H);

    const float area = (float)max(0, y2 - y1) * (float)max(0, x2 - x1);
    const float cnt  = (float)(H * W) - area;
    const float inv  = (cnt > 0.0f) ? (1.0f / fmaxf(cnt, 1.0f)) : 0.0f;

    // inside-row interval in i-space: y1 <= blk+64i < y2
    const int iLo = min(ROWS, max(0, (y1 - blk + 63) >> 6));
    const int iHi = min(ROWS, max(iLo, (y2 - blk + 63) >> 6));

    const float* base = pred + ((size_t)b << 20) + ((size_t)blk << 10);
    const float* pO   = base + (tid << 2);   // this thread's full-row address

    float acc = 0.0f, acc2 = 0.0f;

    // --- outside rows before the bbox: i in [0, iLo), branchless pairs
    {
        int i = 0;
        for (; i + 2 <= iLo; i += 2) {
            const float4 va = *reinterpret_cast<const float4*>(pO + (size_t)i * STR);
            const float4 vb = *reinterpret_cast<const float4*>(pO + (size_t)(i + 1) * STR);
            acc += row4(va);
            acc2 += row4(vb);
        }
        if (i < iLo)
            acc += row4(*reinterpret_cast<const float4*>(pO + (size_t)i * STR));
    }
    // --- outside rows after the bbox: i in [iHi, ROWS)
    {
        int i = iHi;
        for (; i + 2 <= ROWS; i += 2) {
            const float4 va = *reinterpret_cast<const float4*>(pO + (size_t)i * STR);
            const float4 vb = *reinterpret_cast<const float4*>(pO + (size_t)(i + 1) * STR);
            acc += row4(va);
            acc2 += row4(vb);
        }
        if (i < ROWS)
            acc += row4(*reinterpret_cast<const float4*>(pO + (size_t)i * STR));
    }
    // --- inside rows: compacted columns, constant per-element weights
    {
        const int nL   = (x1 + 3) >> 2;     // left-segment float4 count
        const int rS   = x2 >> 2;           // right-segment first float4
        const int nAct = nL + (256 - rS);   // active threads on inside rows
        if (tid < nAct) {
            const int c4 = (tid < nL) ? tid : (rS + tid - nL);
            const int x0 = c4 << 2;
            const float4 w = make_float4(
                (x0 + 0 >= x1 && x0 + 0 < x2) ? 0.0f : 1.0f,
                (x0 + 1 >= x1 && x0 + 1 < x2) ? 0.0f : 1.0f,
                (x0 + 2 >= x1 && x0 + 2 < x2) ? 0.0f : 1.0f,
                (x0 + 3 >= x1 && x0 + 3 < x2) ? 0.0f : 1.0f);
            const float* pI = base + x0;
            int i = iLo;
            for (; i + 2 <= iHi; i += 2) {
                const float4 va = *reinterpret_cast<const float4*>(pI + (size_t)i * STR);
                const float4 vb = *reinterpret_cast<const float4*>(pI + (size_t)(i + 1) * STR);
                acc += row4w(va, w);
                acc2 += row4w(vb, w);
            }
            if (i < iHi)
                acc += row4w(*reinterpret_cast<const float4*>(pI + (size_t)i * STR), w);
        }
    }

    float t = (acc + acc2) * inv;   // batch-agnostic partial (pre-normalized)

    // block reduction: wave shfl, then LDS across 4 waves
    for (int off = 32; off > 0; off >>= 1)
        t += __shfl_down(t, off, 64);
    __shared__ float s[NTHREADS / 64];
    const int wave = tid >> 6;
    if ((tid & 63) == 0) s[wave] = t;
    __syncthreads();
    if (tid == 0)
        ws[g] = s[0] + s[1] + s[2] + s[3];
}

// Kernel 2: one block of 256 threads sums the 2048 partials in a FIXED order
// (deterministic across replays) and writes the scalar mean.
__global__ __launch_bounds__(NTHREADS)
void finalize_kernel(const float* __restrict__ ws, float* __restrict__ out) {
    const int tid = threadIdx.x;
    float t = 0.0f;
    const float* p = ws + (size_t)tid * (NBLK / NTHREADS);
#pragma unroll
    for (int i = 0; i < NBLK / NTHREADS; ++i) t += p[i];
    for (int off = 32; off > 0; off >>= 1)
        t += __shfl_down(t, off, 64);
    __shared__ float s[NTHREADS / 64];
    const int wave = tid >> 6;
    if ((tid & 63) == 0) s[wave] = t;
    __syncthreads();
    if (tid == 0)
        out[0] = (s[0] + s[1] + s[2] + s[3]) * (1.0f / (float)B);
}

extern "C" void kernel_launch(void* const* d_in, const int* in_sizes, int n_in,
                              void* d_out, int out_size, void* d_ws, size_t ws_size,
                              hipStream_t stream) {
    const float* pred   = (const float*)d_in[0];  // (B,1,H,W) f32
    const float* bboxes = (const float*)d_in[1];  // (B,4) f32
    float* out = (float*)d_out;                   // scalar f32
    float* ws  = (float*)d_ws;                    // NBLK float partials (8 KB)

    partial_kernel<<<NBLK, NTHREADS, 0, stream>>>(pred, bboxes, ws);
    finalize_kernel<<<1, NTHREADS, 0, stream>>>(ws, out);
}

// Round 9
// 20.396 us; speedup vs baseline: 1.0779x; 1.0779x over previous
//
#include <hip/hip_runtime.h>
#include <math.h>

// Problem constants (from reference setup_inputs): B=32, H=W=1024.
constexpr int B = 32;
constexpr int H = 1024;
constexpr int W = 1024;
constexpr int BPB  = 64;              // blocks per batch; also the row stride
constexpr int ROWS = H / BPB;         // 16 rows per block (y = blk + 64*i)
constexpr int NBLK = B * BPB;         // 2048 blocks (exactly CU-resident)
constexpr int NTHREADS = 256;         // 256 threads * float4 = one 1024-px row
constexpr int STR = BPB * W;          // floats per i-step (64 rows)

// Accumulate log2((1+eps) - p): eps folded into the constant (1 v_sub vs
// v_sub+v_add), log2 instead of ln (the x ln2 is applied ONCE per block,
// killing ~19M v_mul), weighted rows use fmaf. Error vs reference ~1e-7.
constexpr float KONE = 1.0f + 1e-7f;

__device__ __forceinline__ float row4l2(const float4 v) {
    return __log2f(KONE - v.x) + __log2f(KONE - v.y) +
           __log2f(KONE - v.z) + __log2f(KONE - v.w);
}
__device__ __forceinline__ float row4l2w(const float4 v, const float4 w) {
    float s = w.x * __log2f(KONE - v.x);
    s = fmaf(w.y, __log2f(KONE - v.y), s);
    s = fmaf(w.z, __log2f(KONE - v.z), s);
    s = fmaf(w.w, __log2f(KONE - v.w), s);
    return s;
}

// Kernel 1: per-block partial of sum_outside log2(KONE - p), pre-scaled by
// (-ln2 / cnt_b). R7's proven structure (b = g>>6, branchless 3-loop split
// at the contiguous inside-row interval [iLo,iHi) in i-space), with 4-deep
// load pipelining in the outside loops (4 independent float4 loads in
// flight per wave -> robust to cold-HBM latency).
__global__ __launch_bounds__(NTHREADS)
void partial_kernel(const float* __restrict__ pred,
                    const float* __restrict__ bboxes,
                    float* __restrict__ ws) {
    const int g   = blockIdx.x;
    const int b   = g >> 6;
    const int blk = g & (BPB - 1);
    const int tid = threadIdx.x;

    // bbox -> integer pixel bounds, exactly matching the reference (scalar).
    const int x1 = max((int)floorf(bboxes[b * 4 + 0] * (float)W), 0);
    const int y1 = max((int)floorf(bboxes[b * 4 + 1] * (float)H), 0);
    const int x2 = min((int)floorf(bboxes[b * 4 + 2] * (float)W), W);
    const int y2 = min((int)floorf(bboxes[b * 4 + 3] * (float)H), H);

    const float area = (float)max(0, y2 - y1) * (float)max(0, x2 - x1);
    const float cnt  = (float)(H * W) - area;
    const float inv  = (cnt > 0.0f) ? (1.0f / fmaxf(cnt, 1.0f)) : 0.0f;

    // inside-row interval in i-space: y1 <= blk+64i < y2
    const int iLo = min(ROWS, max(0, (y1 - blk + 63) >> 6));
    const int iHi = min(ROWS, max(iLo, (y2 - blk + 63) >> 6));

    const float* base = pred + ((size_t)b << 20) + ((size_t)blk << 10);
    const float* pO   = base + (tid << 2);   // this thread's full-row address

    float a0 = 0.0f, a1 = 0.0f, a2 = 0.0f, a3 = 0.0f;

    // --- outside rows before the bbox: i in [0, iLo), 4-deep
    {
        int i = 0;
        for (; i + 4 <= iLo; i += 4) {
            const float4 va = *reinterpret_cast<const float4*>(pO + (size_t)(i + 0) * STR);
            const float4 vb = *reinterpret_cast<const float4*>(pO + (size_t)(i + 1) * STR);
            const float4 vc = *reinterpret_cast<const float4*>(pO + (size_t)(i + 2) * STR);
            const float4 vd = *reinterpret_cast<const float4*>(pO + (size_t)(i + 3) * STR);
            a0 += row4l2(va); a1 += row4l2(vb); a2 += row4l2(vc); a3 += row4l2(vd);
        }
        for (; i < iLo; ++i)
            a0 += row4l2(*reinterpret_cast<const float4*>(pO + (size_t)i * STR));
    }
    // --- outside rows after the bbox: i in [iHi, ROWS), 4-deep
    {
        int i = iHi;
        for (; i + 4 <= ROWS; i += 4) {
            const float4 va = *reinterpret_cast<const float4*>(pO + (size_t)(i + 0) * STR);
            const float4 vb = *reinterpret_cast<const float4*>(pO + (size_t)(i + 1) * STR);
            const float4 vc = *reinterpret_cast<const float4*>(pO + (size_t)(i + 2) * STR);
            const float4 vd = *reinterpret_cast<const float4*>(pO + (size_t)(i + 3) * STR);
            a0 += row4l2(va); a1 += row4l2(vb); a2 += row4l2(vc); a3 += row4l2(vd);
        }
        for (; i < ROWS; ++i)
            a0 += row4l2(*reinterpret_cast<const float4*>(pO + (size_t)i * STR));
    }
    // --- inside rows: compacted columns, constant per-element {0,1} weights
    {
        const int nL   = (x1 + 3) >> 2;     // left-segment float4 count
        const int rS   = x2 >> 2;           // right-segment first float4
        const int nAct = nL + (256 - rS);   // active threads on inside rows
        if (tid < nAct) {
            const int c4 = (tid < nL) ? tid : (rS + tid - nL);
            const int x0 = c4 << 2;
            const float4 w = make_float4(
                (x0 + 0 >= x1 && x0 + 0 < x2) ? 0.0f : 1.0f,
                (x0 + 1 >= x1 && x0 + 1 < x2) ? 0.0f : 1.0f,
                (x0 + 2 >= x1 && x0 + 2 < x2) ? 0.0f : 1.0f,
                (x0 + 3 >= x1 && x0 + 3 < x2) ? 0.0f : 1.0f);
            const float* pI = base + x0;
            int i = iLo;
            for (; i + 2 <= iHi; i += 2) {
                const float4 va = *reinterpret_cast<const float4*>(pI + (size_t)(i + 0) * STR);
                const float4 vb = *reinterpret_cast<const float4*>(pI + (size_t)(i + 1) * STR);
                a0 += row4l2w(va, w);
                a1 += row4l2w(vb, w);
            }
            if (i < iHi)
                a0 += row4l2w(*reinterpret_cast<const float4*>(pI + (size_t)i * STR), w);
        }
    }

    // pre-scale: -ln2 / cnt_b  (makes partials batch-agnostic)
    float t = ((a0 + a1) + (a2 + a3)) * (-0.69314718056f * inv);

    // block reduction: wave shfl, then LDS across 4 waves
    for (int off = 32; off > 0; off >>= 1)
        t += __shfl_down(t, off, 64);
    __shared__ float s[NTHREADS / 64];
    const int wave = tid >> 6;
    if ((tid & 63) == 0) s[wave] = t;
    __syncthreads();
    if (tid == 0)
        ws[g] = s[0] + s[1] + s[2] + s[3];
}

// Kernel 2: one block of 256 threads sums the 2048 partials in a FIXED order
// (deterministic across replays) and writes the scalar mean.
__global__ __launch_bounds__(NTHREADS)
void finalize_kernel(const float* __restrict__ ws, float* __restrict__ out) {
    const int tid = threadIdx.x;
    float t = 0.0f;
    const float* p = ws + (size_t)tid * (NBLK / NTHREADS);
#pragma unroll
    for (int i = 0; i < NBLK / NTHREADS; ++i) t += p[i];
    for (int off = 32; off > 0; off >>= 1)
        t += __shfl_down(t, off, 64);
    __shared__ float s[NTHREADS / 64];
    const int wave = tid >> 6;
    if ((tid & 63) == 0) s[wave] = t;
    __syncthreads();
    if (tid == 0)
        out[0] = (s[0] + s[1] + s[2] + s[3]) * (1.0f / (float)B);
}

extern "C" void kernel_launch(void* const* d_in, const int* in_sizes, int n_in,
                              void* d_out, int out_size, void* d_ws, size_t ws_size,
                              hipStream_t stream) {
    const float* pred   = (const float*)d_in[0];  // (B,1,H,W) f32
    const float* bboxes = (const float*)d_in[1];  // (B,4) f32
    float* out = (float*)d_out;                   // scalar f32
    float* ws  = (float*)d_ws;                    // NBLK float partials (8 KB)

    partial_kernel<<<NBLK, NTHREADS, 0, stream>>>(pred, bboxes, ws);
    finalize_kernel<<<1, NTHREADS, 0, stream>>>(ws, out);
}